// Round 4
// baseline (673.666 us; speedup 1.0000x reference)
//
#include <hip/hip_runtime.h>

#define B_CNT 4
#define N_CNT 10000
#define E_CNT 100000

typedef __attribute__((ext_vector_type(8))) short s16x8;
typedef __attribute__((ext_vector_type(4))) float f32x4;
typedef __attribute__((ext_vector_type(4))) unsigned int u32x4;

__device__ __forceinline__ float b2f(unsigned short u) {
  union { unsigned int i; float f; } v; v.i = ((unsigned int)u) << 16; return v.f;
}
__device__ __forceinline__ unsigned short f2b(float f) {
  union { float f; unsigned int i; } v; v.f = f;
  unsigned int b = v.i;
  b += 0x7FFFu + ((b >> 16) & 1u);   // round-to-nearest-even
  return (unsigned short)(b >> 16);
}
// packed fp32 pair -> bf16x2 (RNE), one VALU op
__device__ __forceinline__ unsigned int cvtpk(float lo, float hi) {
  unsigned int r;
  asm("v_cvt_pk_bf16_f32 %0, %1, %2" : "=v"(r) : "v"(lo), "v"(hi));
  return r;
}
__device__ __forceinline__ void keeps(s16x8 v) {
  u32x4 u = __builtin_bit_cast(u32x4, v);
  asm volatile("" :: "v"(u.x), "v"(u.y), "v"(u.z), "v"(u.w));
}

// ---------------------------------------------------------------------------
// K_PREP: fused {fft (blocks 0..39)} ∪ {pack (40..71)} ∪ {cnt (72..462)}.
// All three are independent; fusing saves 2 dispatches of launch overhead.
// ---------------------------------------------------------------------------
__global__ void k_prep(const float* __restrict__ x,
                       const float* __restrict__ tcwr,
                       const float* __restrict__ tcwi,
                       float* __restrict__ xnew,
                       const float* __restrict__ w1,
                       const float* __restrict__ w2,
                       unsigned short* __restrict__ pw1,
                       unsigned short* __restrict__ pw2,
                       const int* __restrict__ eidx,
                       int* __restrict__ cnt) {
  const int bid = blockIdx.x;
  const int t = threadIdx.x;
  if (bid < 40) {
    // ---- spectral transform (closed-form rfft/irfft over batch, n=4) ----
    __shared__ float Wr[256], Wi[256];
    Wr[t] = tcwr[t * 2] + tcwr[t * 2 + 1];
    Wi[t] = tcwi[t * 2] + tcwi[t * 2 + 1];
    __syncthreads();
    const int n = bid * 256 + t;
    if (n >= N_CNT) return;
    float xt[4][16];
    for (int tt = 0; tt < 4; ++tt) {
      const float* xp = x + ((size_t)tt * N_CNT + n) * 16;
#pragma unroll
      for (int i0 = 0; i0 < 16; i0 += 4) {
        const float4 v = *(const float4*)(xp + i0);
        xt[tt][i0 + 0] = v.x; xt[tt][i0 + 1] = v.y;
        xt[tt][i0 + 2] = v.z; xt[tt][i0 + 3] = v.w;
      }
    }
    float s[16], a[16], bb[16];
#pragma unroll
    for (int i = 0; i < 16; ++i) {
      s[i]  = xt[0][i] + xt[1][i] + xt[2][i] + xt[3][i];
      a[i]  = xt[0][i] - xt[2][i];
      bb[i] = xt[1][i] - xt[3][i];
    }
    for (int o = 0; o < 16; ++o) {
      float r0 = 0.f, p = 0.f, qq = 0.f;
#pragma unroll
      for (int i = 0; i < 16; ++i) {
        const float wr = Wr[i * 16 + o], wi = Wi[i * 16 + o];
        r0 += s[i] * wr;
        p  += a[i] * wr + bb[i] * wi;
        qq += a[i] * wi - bb[i] * wr;
      }
      xnew[((size_t)0 * N_CNT + n) * 16 + o] = 0.25f * (r0 + 2.f * p);
      xnew[((size_t)1 * N_CNT + n) * 16 + o] = 0.25f * (r0 - 2.f * qq);
      xnew[((size_t)2 * N_CNT + n) * 16 + o] = 0.25f * (r0 - 2.f * p);
      xnew[((size_t)3 * N_CNT + n) * 16 + o] = 0.25f * (r0 + 2.f * qq);
    }
  } else if (bid < 72) {
    // ---- pack W1/W2 fp32 -> bf16 MFMA B-fragment order ----
    const int tg = (bid - 40) * 256 + t;  // 0..8191
    const int tile = tg >> 6, l = tg & 63, q = l >> 4, lm = l & 15;
    if (tile < 32) {
      const int nt = tile >> 2, kk = tile & 3;
      const int n = nt * 16 + lm;
      unsigned short* dst = pw1 + ((size_t)tile * 64 + l) * 8;
#pragma unroll
      for (int j = 0; j < 8; ++j) dst[j] = f2b(w1[(kk * 32 + q * 8 + j) * 128 + n]);
    } else {
      const int t2 = tile - 32;  // 0..95
      const int nt = t2 >> 2, kk = t2 & 3;
      int col;
      if (nt < 16) col = nt * 16 + lm;
      else col = 256 + (8 * (lm & 1) + (nt - 16)) * 8 + (lm >> 1);
      unsigned short* dst = pw2 + ((size_t)t2 * 64 + l) * 8;
#pragma unroll
      for (int j = 0; j < 8; ++j) dst[j] = f2b(w2[(kk * 32 + q * 8 + j) * 384 + col]);
    }
  } else {
    // ---- in-degree histogram ----
    const int e = (bid - 72) * 256 + t;
    if (e < E_CNT) atomicAdd(&cnt[eidx[E_CNT + e]], 1);
  }
}

// ---------------------------------------------------------------------------
// K_SCAN: exclusive prefix scan of cnt -> rowstart[10001] + 4 per-batch
// runoff copies (slot cursors claimed by k_edge's inline atomics).
// ---------------------------------------------------------------------------
__global__ void k_scan(const int* __restrict__ cnt, int* __restrict__ rowstart,
                       int* __restrict__ runoff4) {
  __shared__ int partial[256];
  const int t = threadIdx.x;
  const int c0 = t * 40;
  int s = 0;
  for (int j = 0; j < 40; ++j) {
    const int idx = c0 + j;
    if (idx < N_CNT) s += cnt[idx];
  }
  partial[t] = s;
  __syncthreads();
  if (t == 0) {
    int acc = 0;
    for (int i = 0; i < 256; ++i) { const int v = partial[i]; partial[i] = acc; acc += v; }
  }
  __syncthreads();
  int acc = partial[t];
  for (int j = 0; j < 40; ++j) {
    const int idx = c0 + j;
    if (idx < N_CNT) {
      rowstart[idx] = acc;
      runoff4[idx] = acc;
      runoff4[N_CNT + idx] = acc;
      runoff4[2 * N_CNT + idx] = acc;
      runoff4[3 * N_CNT + idx] = acc;
      acc += cnt[idx];
    }
  }
  if (t == 255) rowstart[N_CNT] = acc;  // == E_CNT
}

// ---------------------------------------------------------------------------
// K4: fused edge kernel. Per block: 32 edges, one batch.
//   GEMM1: H(32x128) = relu(EA @ W1 + b1)   (16 A-loads clustered via
//          sched_barrier(0) -> all in flight, one latency exposure)
//   GEMM2: EW(32x384) = H @ W2 + b2
//   Hs and EWt OVERLAID in one LDS buffer (never live simultaneously;
//   extra barrier between GEMM2 reads and EWt stores). LDS 28.3 KB ->
//   5 blocks/CU. EWt half-swizzled (8-way store floor).
//   CSR slot claimed inline in phase 0: ids[el]=atomicAdd(runoff4[b][dst]).
// ---------------------------------------------------------------------------
template <bool ATOMIC>
__global__ __launch_bounds__(256, 5) void k_edge(
    const float* __restrict__ ea, const int* __restrict__ eidx,
    const float* __restrict__ esh,
    const unsigned short* __restrict__ pw1, const unsigned short* __restrict__ pw2,
    const float* __restrict__ b1v, const float* __restrict__ b2v,
    const float* __restrict__ xnew, int* __restrict__ slot,
    float* __restrict__ out_base, const size_t bstride) {
  __shared__ __align__(16) unsigned short U[32 * 392];  // Hs[32*136] ∪ EWt[32*392]
  unsigned short* const Hs = U;
  unsigned short* const EWt = U;
  __shared__ float xgs[32 * 20];                        // 16 + 4 pad
  __shared__ float shs[32 * 4];
  __shared__ int ids[32];

  const int t = threadIdx.x;
  const int b = blockIdx.y;
  const int e0 = blockIdx.x * 32;
  const int w = t >> 6, l = t & 63, q = l >> 4, lm = l & 15;

  // ---- phase 0: stage xg (gather), sh, slot/dst ids ----
  if (t < 128) {
    const int el = t >> 2, i0 = (t & 3) * 4;
    const int src = eidx[e0 + el];
    const float4 v = *(const float4*)(xnew + ((size_t)b * N_CNT + src) * 16 + i0);
    xgs[el * 20 + i0 + 0] = v.x;
    xgs[el * 20 + i0 + 1] = v.y;
    xgs[el * 20 + i0 + 2] = v.z;
    xgs[el * 20 + i0 + 3] = v.w;
  } else if (t < 160) {
    const int el = t - 128;
    const float4 v = *(const float4*)(esh + ((size_t)b * E_CNT + e0 + el) * 4);
    shs[el * 4 + 0] = v.x;
    shs[el * 4 + 1] = v.y;
    shs[el * 4 + 2] = v.z;
    shs[el * 4 + 3] = v.w;
  } else if (t < 192) {
    const int el = t - 160;
    const int dst = eidx[E_CNT + e0 + el];
    if (ATOMIC) ids[el] = dst;
    else ids[el] = atomicAdd(&slot[(size_t)b * N_CNT + dst], 1);
  }

  // ---- GEMM1: issue ALL 16 A-loads, hard scheduling fence, then compute ----
  const float* eab = ea + (size_t)b * E_CNT * 128;
  float4 araw[4][2][2];
#pragma unroll
  for (int kk = 0; kk < 4; ++kk)
#pragma unroll
    for (int mt = 0; mt < 2; ++mt) {
      const float* ap = eab + ((size_t)(e0 + mt * 16 + lm)) * 128 + kk * 32 + q * 8;
      araw[kk][mt][0] = *(const float4*)ap;
      araw[kk][mt][1] = *(const float4*)(ap + 4);
    }
  __builtin_amdgcn_sched_barrier(0);   // nothing crosses: all 16 loads in flight

  s16x8 bfr[2][4];
#pragma unroll
  for (int j = 0; j < 2; ++j)
#pragma unroll
    for (int kk = 0; kk < 4; ++kk)
      bfr[j][kk] = *(const s16x8*)(pw1 + (((size_t)(2 * w + j) * 4 + kk) * 64 + l) * 8);

  f32x4 acc1[2][2];
#pragma unroll
  for (int mt = 0; mt < 2; ++mt)
#pragma unroll
    for (int j = 0; j < 2; ++j) acc1[mt][j] = (f32x4)0.0f;

#pragma unroll
  for (int kk = 0; kk < 4; ++kk) {
#pragma unroll
    for (int mt = 0; mt < 2; ++mt) {
      const float4 a0 = araw[kk][mt][0];
      const float4 a1 = araw[kk][mt][1];
      union { unsigned int u[4]; s16x8 s; } au;
      au.u[0] = cvtpk(a0.x, a0.y); au.u[1] = cvtpk(a0.z, a0.w);
      au.u[2] = cvtpk(a1.x, a1.y); au.u[3] = cvtpk(a1.z, a1.w);
      const s16x8 af = au.s;
      acc1[mt][0] = __builtin_amdgcn_mfma_f32_16x16x32_bf16(af, bfr[0][kk], acc1[mt][0], 0, 0, 0);
      acc1[mt][1] = __builtin_amdgcn_mfma_f32_16x16x32_bf16(af, bfr[1][kk], acc1[mt][1], 0, 0, 0);
    }
  }

  // prefetch GEMM2 B-fragments for kk=0 (independent of Hs)
  s16x8 bw0[6];
#pragma unroll
  for (int jj = 0; jj < 6; ++jj)
    bw0[jj] = *(const s16x8*)(pw2 + (((size_t)(6 * w + jj) * 4 + 0) * 64 + l) * 8);

  // ---- GEMM1 epilogue: bias+relu, pair-convert, scalar Hs stores ----
#pragma unroll
  for (int j = 0; j < 2; ++j) {
    const int n = (2 * w + j) * 16 + lm;
    const float bias = b1v[n];
#pragma unroll
    for (int mt = 0; mt < 2; ++mt) {
#pragma unroll
      for (int r = 0; r < 4; r += 2) {
        const float v0 = fmaxf(acc1[mt][j][r] + bias, 0.0f);
        const float v1 = fmaxf(acc1[mt][j][r + 1] + bias, 0.0f);
        const unsigned int pr = cvtpk(v0, v1);
        Hs[(mt * 16 + q * 4 + r) * 136 + n] = (unsigned short)pr;
        Hs[(mt * 16 + q * 4 + r + 1) * 136 + n] = (unsigned short)(pr >> 16);
      }
    }
  }
#pragma unroll
  for (int jj = 0; jj < 6; ++jj) keeps(bw0[jj]);   // pin across barrier
  __syncthreads();                                 // barrier 1: Hs + staging ready

  // ---- GEMM2 ----
  f32x4 acc2[2][6];
#pragma unroll
  for (int mt = 0; mt < 2; ++mt)
#pragma unroll
    for (int jj = 0; jj < 6; ++jj) acc2[mt][jj] = (f32x4)0.0f;

#pragma unroll
  for (int kk = 0; kk < 4; ++kk) {
    s16x8 bw[6];
    if (kk == 0) {
#pragma unroll
      for (int jj = 0; jj < 6; ++jj) bw[jj] = bw0[jj];
    } else {
#pragma unroll
      for (int jj = 0; jj < 6; ++jj)
        bw[jj] = *(const s16x8*)(pw2 + (((size_t)(6 * w + jj) * 4 + kk) * 64 + l) * 8);
    }
#pragma unroll
    for (int mt = 0; mt < 2; ++mt) {
      const s16x8 ah = *(const s16x8*)(&Hs[(mt * 16 + lm) * 136 + kk * 32 + q * 8]);
#pragma unroll
      for (int jj = 0; jj < 6; ++jj)
        acc2[mt][jj] = __builtin_amdgcn_mfma_f32_16x16x32_bf16(ah, bw[jj], acc2[mt][jj], 0, 0, 0);
    }
  }
  __syncthreads();                                 // barrier 2: Hs reads done (overlay!)

  // ---- epilogue 2: bias + cvt_pk, HALF-SWIZZLED b32 stores ----
  // logical: tile T=6w+jj: T<16 -> (ch=lm, i=T); T>=16 -> (ch=16+(lm>>1), i=8*(l&1)+T-16)
  // physical 16B-half = logical half ^ (q&1)  [= (edge>>2)&1 for this lane's edges]
  float bias6[6];
#pragma unroll
  for (int jj = 0; jj < 6; ++jj) {
    const int T = 6 * w + jj;
    const int bcol = (T < 16) ? (T * 16 + lm)
                              : (256 + (8 * (l & 1) + (T - 16)) * 8 + (lm >> 1));
    bias6[jj] = b2v[bcol];
  }
  const int sq4 = (q & 1) * 4;          // swizzle offset for half 0
  const int nsq4 = 4 - sq4;             // swizzle offset for half 1
  const int ch2off = (16 + (lm >> 1)) * 8 + (((l & 1) ^ (q & 1)) ? 4 : 0);
#pragma unroll
  for (int mt = 0; mt < 2; ++mt)
#pragma unroll
    for (int r = 0; r < 4; ++r) {
      const int edge = mt * 16 + q * 4 + r;
      const unsigned int p0 = cvtpk(acc2[mt][0][r] + bias6[0], acc2[mt][1][r] + bias6[1]);
      const unsigned int p1 = cvtpk(acc2[mt][2][r] + bias6[2], acc2[mt][3][r] + bias6[3]);
      const unsigned int p2 = cvtpk(acc2[mt][4][r] + bias6[4], acc2[mt][5][r] + bias6[5]);
      unsigned int* base = (unsigned int*)&EWt[edge * 392];
      if (w == 0) {                      // dwords 0,1,2 of ch=lm (half0 pos0-2)
        unsigned int* d = base + lm * 8 + sq4;
        d[0] = p0; d[1] = p1; d[2] = p2;
      } else if (w == 1) {               // dword3 (h0p3), dwords 4,5 (h1 p0,1)
        base[lm * 8 + sq4 + 3] = p0;
        unsigned int* d = base + lm * 8 + nsq4;
        d[0] = p1; d[1] = p2;
      } else if (w == 2) {               // dwords 6,7 (h1 p2,3); ch2 h=(l&1) p0
        unsigned int* d = base + lm * 8 + nsq4 + 2;
        d[0] = p0; d[1] = p1;
        base[ch2off] = p2;
      } else {                           // ch2 h=(l&1) pos 1,2,3
        unsigned int* d = base + ch2off + 1;
        d[0] = p0; d[1] = p1; d[2] = p2;
      }
    }
  __syncthreads();                                 // barrier 3: EWt ready

  // ---- phase 3: 24 dots/edge, 3 per thread, half-swapped b128 LDS reads ----
  {
    const int m = t >> 3, sub = t & 7;
    const int sqr8 = ((m >> 2) & 1) << 3;    // read-side half swap
    float xr[16];
#pragma unroll
    for (int i0 = 0; i0 < 16; i0 += 4) {
      const float4 v = *(const float4*)&xgs[m * 20 + i0];
      xr[i0] = v.x; xr[i0 + 1] = v.y; xr[i0 + 2] = v.z; xr[i0 + 3] = v.w;
    }
    const float sh0v = 0.25f * shs[m * 4 + 0];   // ALPHA = 1/sqrt(16)
    const float s1a = 0.25f * shs[m * 4 + 1];
    const float s1b = 0.25f * shs[m * 4 + 2];
    const float s1c = 0.25f * shs[m * 4 + 3];
    float* outp = out_base + (size_t)b * bstride + (size_t)ids[m] * 40;
#pragma unroll
    for (int dd = 0; dd < 3; ++dd) {
      const int d = sub * 3 + dd;                // 0..23 == EWt channel
      const unsigned short* ep = &EWt[m * 392 + d * 16];
      const s16x8 eA = *(const s16x8*)(ep + sqr8);
      const s16x8 eB = *(const s16x8*)(ep + 8 - sqr8);
      float dotv = 0.f;
#pragma unroll
      for (int i = 0; i < 8; ++i) {
        dotv += xr[i] * b2f((unsigned short)eA[i]);
        dotv += xr[8 + i] * b2f((unsigned short)eB[i]);
      }
      if (d < 16) {
        const float val = dotv * sh0v;
        if (ATOMIC) atomicAdd(outp + d, val); else outp[d] = val;
      } else {
        const int c0 = 16 + (d - 16) * 3;
        if (ATOMIC) {
          atomicAdd(outp + c0 + 0, dotv * s1a);
          atomicAdd(outp + c0 + 1, dotv * s1b);
          atomicAdd(outp + c0 + 2, dotv * s1c);
        } else {
          outp[c0 + 0] = dotv * s1a;
          outp[c0 + 1] = dotv * s1b;
          outp[c0 + 2] = dotv * s1c;
        }
      }
    }
  }
}

// ---------------------------------------------------------------------------
// K5 (fallback only): agg = sums / max(cnt,1) + per-channel partials.
// ---------------------------------------------------------------------------
__global__ void k_agg(float* __restrict__ sums, const int* __restrict__ cnt,
                      float* __restrict__ psum, float* __restrict__ psq) {
  __shared__ float ls[40], lq[40];
  const int t = threadIdx.x;
  if (t < 40) { ls[t] = 0.f; lq[t] = 0.f; }
  __syncthreads();
  const unsigned base = blockIdx.x * 2048u + t;
  for (int k2 = 0; k2 < 8; ++k2) {
    const unsigned idx = base + k2 * 256u;
    if (idx < 1600000u) {
      const unsigned row = idx / 40u;
      const unsigned node = row % 10000u;
      const float c = (float)cnt[node];
      const float v = sums[idx] / fmaxf(c, 1.f);
      sums[idx] = v;
      const unsigned ch = idx - row * 40u;
      atomicAdd(&ls[ch], v);
      atomicAdd(&lq[ch], v * v);
    }
  }
  __syncthreads();
  if (t < 40) {
    atomicAdd(&psum[t], ls[t]);
    atomicAdd(&psq[t], lq[t]);
  }
}

// ---------------------------------------------------------------------------
// K5b (CSR): gather rows per (b,node), mean-divide, BN partials.
// ---------------------------------------------------------------------------
__global__ __launch_bounds__(256) void k_gather(
    const float* __restrict__ msgbuf, const int* __restrict__ rowstart,
    float* __restrict__ sums, float* __restrict__ psum, float* __restrict__ psq) {
  const int t = threadIdx.x;
  const int wid = t >> 6, ch = t & 63;
  if (ch >= 40) return;
  float lsum = 0.f, lsq = 0.f;
  for (int k = 0; k < 8; ++k) {
    const int p = blockIdx.x * 32 + wid * 8 + k;   // 0..39999 = b*10000+node
    const int bb = p / 10000;
    const int node = p - bb * 10000;
    const int r0 = rowstart[node], r1 = rowstart[node + 1];
    const float* base = msgbuf + (size_t)bb * (E_CNT * 40) + ch;
    float v0 = 0.f, v1 = 0.f, v2 = 0.f, v3 = 0.f;
    int r = r0;
    for (; r + 4 <= r1; r += 4) {
      v0 += base[(size_t)(r + 0) * 40];
      v1 += base[(size_t)(r + 1) * 40];
      v2 += base[(size_t)(r + 2) * 40];
      v3 += base[(size_t)(r + 3) * 40];
    }
    for (; r < r1; ++r) v0 += base[(size_t)r * 40];
    float v = (v0 + v1) + (v2 + v3);
    v /= fmaxf((float)(r1 - r0), 1.f);
    sums[(size_t)p * 40 + ch] = v;
    lsum += v; lsq += v * v;
  }
  atomicAdd(&psum[ch], lsum);
  atomicAdd(&psq[ch], lsq);
}

// ---------------------------------------------------------------------------
// K7: BN finalize (per-block, from partials) + normalize + fp32 output.
// ---------------------------------------------------------------------------
__global__ void k_out(const float* __restrict__ agg,
                      const float* __restrict__ psum, const float* __restrict__ psq,
                      const float* __restrict__ gma, const float* __restrict__ bta,
                      float* __restrict__ outp) {
  __shared__ float sc[40], sh[40];
  const int t = threadIdx.x;
  if (t < 40) {
    const float inv = 1.0f / 40000.0f;  // B*N rows
    const float mu = psum[t] * inv;
    const float var = psq[t] * inv - mu * mu;
    const float s = rsqrtf(fmaxf(var, 0.0f) + 1e-5f) * gma[t];
    sc[t] = s;
    sh[t] = bta[t] - mu * s;
  }
  __syncthreads();
  const unsigned base = blockIdx.x * 1024u + t;
#pragma unroll
  for (int k2 = 0; k2 < 4; ++k2) {
    const unsigned idx = base + k2 * 256u;
    if (idx < 1600000u) {
      const unsigned row = idx / 40u;
      const unsigned ch = idx - row * 40u;
      outp[idx] = agg[idx] * sc[ch] + sh[ch];
    }
  }
}

// ---------------------------------------------------------------------------
// Workspace layout (bytes):
//   [0)          sums      6,400,000   (CSR: written by k_gather; FB: zeroed)
//   [6,400,000)  cnt          40,000   (zeroed)
//   [6,440,000)  psum            160   (zeroed)
//   [6,440,160)  psq             160   (zeroed)
//   [6,440,448)  xnew      2,560,000
//   [9,000,448)  pw1          32,768
//   [9,033,216)  pw2          98,304
//   [9,131,840)  rowstart     40,016   (10001 ints)           } CSR only
//   [9,171,872)  runoff4     160,000   (4 x 10000 ints)       }
//   [9,331,872)  msgbuf   64,000,000                          }
// CSR total 73,331,872
// ---------------------------------------------------------------------------
extern "C" void kernel_launch(void* const* d_in, const int* in_sizes, int n_in,
                              void* d_out, int out_size, void* d_ws, size_t ws_size,
                              hipStream_t stream) {
  (void)in_sizes; (void)n_in; (void)out_size;
  const float* x    = (const float*)d_in[0];
  const int*   eidx = (const int*)d_in[1];
  const float* ea   = (const float*)d_in[2];
  const float* esh  = (const float*)d_in[3];
  const float* tcwr = (const float*)d_in[4];
  const float* tcwi = (const float*)d_in[5];
  const float* w1   = (const float*)d_in[6];
  const float* b1   = (const float*)d_in[7];
  const float* w2   = (const float*)d_in[8];
  const float* b2   = (const float*)d_in[9];
  const float* gma  = (const float*)d_in[10];
  const float* bta  = (const float*)d_in[11];

  char* ws = (char*)d_ws;
  float*          sums     = (float*)(ws + 0);
  int*            cnt      = (int*)(ws + 6400000);
  float*          psum     = (float*)(ws + 6440000);
  float*          psq      = (float*)(ws + 6440160);
  float*          xnew     = (float*)(ws + 6440448);
  unsigned short* pw1      = (unsigned short*)(ws + 9000448);
  unsigned short* pw2      = (unsigned short*)(ws + 9033216);
  int*            rowstart = (int*)(ws + 9131840);
  int*            runoff4  = (int*)(ws + 9171872);
  float*          msgbuf   = (float*)(ws + 9331872);

  const bool use_csr = ws_size >= (size_t)73331872;

  if (use_csr) {
    hipMemsetAsync(ws + 6400000, 0, 40320, stream);  // cnt + psum + psq
    k_prep<<<dim3(463), dim3(256), 0, stream>>>(x, tcwr, tcwi, xnew, w1, w2,
                                                pw1, pw2, eidx, cnt);
    k_scan<<<dim3(1), dim3(256), 0, stream>>>(cnt, rowstart, runoff4);
    k_edge<false><<<dim3(E_CNT / 32, B_CNT), dim3(256), 0, stream>>>(
        ea, eidx, esh, pw1, pw2, b1, b2, xnew, runoff4, msgbuf, (size_t)E_CNT * 40);
    k_gather<<<dim3(1250), dim3(256), 0, stream>>>(msgbuf, rowstart, sums, psum, psq);
    k_out<<<dim3(1563), dim3(256), 0, stream>>>(sums, psum, psq, gma, bta, (float*)d_out);
  } else {
    hipMemsetAsync(ws, 0, 6440320, stream);
    k_prep<<<dim3(463), dim3(256), 0, stream>>>(x, tcwr, tcwi, xnew, w1, w2,
                                                pw1, pw2, eidx, cnt);
    k_edge<true><<<dim3(E_CNT / 32, B_CNT), dim3(256), 0, stream>>>(
        ea, eidx, esh, pw1, pw2, b1, b2, xnew, nullptr, sums, (size_t)N_CNT * 40);
    k_agg<<<dim3(782), dim3(256), 0, stream>>>(sums, cnt, psum, psq);
    k_out<<<dim3(1563), dim3(256), 0, stream>>>(sums, psum, psq, gma, bta, (float*)d_out);
  }
}

// Round 5
// 589.105 us; speedup vs baseline: 1.1435x; 1.1435x over previous
//
#include <hip/hip_runtime.h>

#define B_CNT 4
#define N_CNT 10000
#define E_CNT 100000

typedef __attribute__((ext_vector_type(8))) short s16x8;
typedef __attribute__((ext_vector_type(4))) float f32x4;
typedef __attribute__((ext_vector_type(4))) unsigned int u32x4;

__device__ __forceinline__ float b2f(unsigned short u) {
  union { unsigned int i; float f; } v; v.i = ((unsigned int)u) << 16; return v.f;
}
__device__ __forceinline__ unsigned short f2b(float f) {
  union { float f; unsigned int i; } v; v.f = f;
  unsigned int b = v.i;
  b += 0x7FFFu + ((b >> 16) & 1u);   // round-to-nearest-even
  return (unsigned short)(b >> 16);
}
// packed fp32 pair -> bf16x2 (RNE), one VALU op
__device__ __forceinline__ unsigned int cvtpk(float lo, float hi) {
  unsigned int r;
  asm("v_cvt_pk_bf16_f32 %0, %1, %2" : "=v"(r) : "v"(lo), "v"(hi));
  return r;
}
__device__ __forceinline__ void keeps(s16x8 v) {
  u32x4 u = __builtin_bit_cast(u32x4, v);
  asm volatile("" :: "v"(u.x), "v"(u.y), "v"(u.z), "v"(u.w));
}
// async global->LDS DMA, 16 B per lane (dst = uniform base + lane*16)
__device__ __forceinline__ void gld16(const void* g, void* l) {
  __builtin_amdgcn_global_load_lds(
      (const __attribute__((address_space(1))) unsigned int*)g,
      (__attribute__((address_space(3))) unsigned int*)l, 16, 0, 0);
}

// ---------------------------------------------------------------------------
// K_PREP: fused {fft (blocks 0..39)} ∪ {pack (40..71)} ∪ {cnt (72..462)}.
// ---------------------------------------------------------------------------
__global__ void k_prep(const float* __restrict__ x,
                       const float* __restrict__ tcwr,
                       const float* __restrict__ tcwi,
                       float* __restrict__ xnew,
                       const float* __restrict__ w1,
                       const float* __restrict__ w2,
                       unsigned short* __restrict__ pw1,
                       unsigned short* __restrict__ pw2,
                       const int* __restrict__ eidx,
                       int* __restrict__ cnt) {
  const int bid = blockIdx.x;
  const int t = threadIdx.x;
  if (bid < 40) {
    // ---- spectral transform (closed-form rfft/irfft over batch, n=4) ----
    __shared__ float Wr[256], Wi[256];
    Wr[t] = tcwr[t * 2] + tcwr[t * 2 + 1];
    Wi[t] = tcwi[t * 2] + tcwi[t * 2 + 1];
    __syncthreads();
    const int n = bid * 256 + t;
    if (n >= N_CNT) return;
    float xt[4][16];
    for (int tt = 0; tt < 4; ++tt) {
      const float* xp = x + ((size_t)tt * N_CNT + n) * 16;
#pragma unroll
      for (int i0 = 0; i0 < 16; i0 += 4) {
        const float4 v = *(const float4*)(xp + i0);
        xt[tt][i0 + 0] = v.x; xt[tt][i0 + 1] = v.y;
        xt[tt][i0 + 2] = v.z; xt[tt][i0 + 3] = v.w;
      }
    }
    float s[16], a[16], bb[16];
#pragma unroll
    for (int i = 0; i < 16; ++i) {
      s[i]  = xt[0][i] + xt[1][i] + xt[2][i] + xt[3][i];
      a[i]  = xt[0][i] - xt[2][i];
      bb[i] = xt[1][i] - xt[3][i];
    }
    for (int o = 0; o < 16; ++o) {
      float r0 = 0.f, p = 0.f, qq = 0.f;
#pragma unroll
      for (int i = 0; i < 16; ++i) {
        const float wr = Wr[i * 16 + o], wi = Wi[i * 16 + o];
        r0 += s[i] * wr;
        p  += a[i] * wr + bb[i] * wi;
        qq += a[i] * wi - bb[i] * wr;
      }
      xnew[((size_t)0 * N_CNT + n) * 16 + o] = 0.25f * (r0 + 2.f * p);
      xnew[((size_t)1 * N_CNT + n) * 16 + o] = 0.25f * (r0 - 2.f * qq);
      xnew[((size_t)2 * N_CNT + n) * 16 + o] = 0.25f * (r0 - 2.f * p);
      xnew[((size_t)3 * N_CNT + n) * 16 + o] = 0.25f * (r0 + 2.f * qq);
    }
  } else if (bid < 72) {
    // ---- pack W1/W2 fp32 -> bf16 MFMA B-fragment order ----
    const int tg = (bid - 40) * 256 + t;  // 0..8191
    const int tile = tg >> 6, l = tg & 63, q = l >> 4, lm = l & 15;
    if (tile < 32) {
      const int nt = tile >> 2, kk = tile & 3;
      const int n = nt * 16 + lm;
      unsigned short* dst = pw1 + ((size_t)tile * 64 + l) * 8;
#pragma unroll
      for (int j = 0; j < 8; ++j) dst[j] = f2b(w1[(kk * 32 + q * 8 + j) * 128 + n]);
    } else {
      const int t2 = tile - 32;  // 0..95
      const int nt = t2 >> 2, kk = t2 & 3;
      int col;
      if (nt < 16) col = nt * 16 + lm;
      else col = 256 + (8 * (lm & 1) + (nt - 16)) * 8 + (lm >> 1);
      unsigned short* dst = pw2 + ((size_t)t2 * 64 + l) * 8;
#pragma unroll
      for (int j = 0; j < 8; ++j) dst[j] = f2b(w2[(kk * 32 + q * 8 + j) * 384 + col]);
    }
  } else {
    // ---- in-degree histogram ----
    const int e = (bid - 72) * 256 + t;
    if (e < E_CNT) atomicAdd(&cnt[eidx[E_CNT + e]], 1);
  }
}

// ---------------------------------------------------------------------------
// K_SCAN: exclusive prefix scan of cnt -> rowstart[10001], runoff copy.
// ---------------------------------------------------------------------------
__global__ void k_scan(const int* __restrict__ cnt, int* __restrict__ rowstart,
                       int* __restrict__ runoff) {
  __shared__ int partial[256];
  const int t = threadIdx.x;
  const int c0 = t * 40;
  int s = 0;
  for (int j = 0; j < 40; ++j) {
    const int idx = c0 + j;
    if (idx < N_CNT) s += cnt[idx];
  }
  partial[t] = s;
  __syncthreads();
  if (t == 0) {
    int acc = 0;
    for (int i = 0; i < 256; ++i) { const int v = partial[i]; partial[i] = acc; acc += v; }
  }
  __syncthreads();
  int acc = partial[t];
  for (int j = 0; j < 40; ++j) {
    const int idx = c0 + j;
    if (idx < N_CNT) { rowstart[idx] = acc; runoff[idx] = acc; acc += cnt[idx]; }
  }
  if (t == 255) rowstart[N_CNT] = acc;  // == E_CNT
}

// ---------------------------------------------------------------------------
// K_POS: per-edge slot assignment within its dst group (CSR permutation).
// ---------------------------------------------------------------------------
__global__ void k_pos(const int* __restrict__ eidx, int* __restrict__ runoff,
                      int* __restrict__ pos) {
  const int e = blockIdx.x * 256 + threadIdx.x;
  if (e < E_CNT) pos[e] = atomicAdd(&runoff[eidx[E_CNT + e]], 1);
}

// ---------------------------------------------------------------------------
// K4: fused edge kernel. Per block: 32 edges, one batch.
//   A-tile (32x128 fp32, 16 KB) DMA'd to LDS via global_load_lds width=16,
//   XOR-granule-swizzled on the GLOBAL source (LDS dest stays linear):
//     physical granule p = e*32 + (g ^ (e&7)),  granule = 16 B = 4 floats.
//   GEMM1 reads ds_read_b128 at granule (g ^ (lm&7)) -> 2 lanes/bank (free).
//   A-tile OVERLAYS EWt (A dead after GEMM1, EWt written after GEMM2).
//   GEMM2 from Hs (separate). EWt half-swizzled (8-way store floor).
//   phase 3: 24 dots/edge, b128 LDS reads, plain stores via pos[] (CSR).
//   LDS 36,992 B -> 4 blocks/CU.
// ---------------------------------------------------------------------------
template <bool ATOMIC>
__global__ __launch_bounds__(256, 4) void k_edge(
    const float* __restrict__ ea, const int* __restrict__ eidx,
    const float* __restrict__ esh,
    const unsigned short* __restrict__ pw1, const unsigned short* __restrict__ pw2,
    const float* __restrict__ b1v, const float* __restrict__ b2v,
    const float* __restrict__ xnew, const int* __restrict__ idx_arr,
    float* __restrict__ out_base, const size_t bstride) {
  __shared__ __align__(16) unsigned short U[32 * 392];   // A-tile(16KB) ∪ EWt(25KB)
  __shared__ __align__(16) unsigned short Hs[32 * 136];  // [edge][k], +8 pad
  __shared__ float xgs[32 * 20];                         // 16 + 4 pad
  __shared__ float shs[32 * 4];
  __shared__ int ids[32];
  unsigned short* const EWt = U;
  const float* const Af = (const float*)U;

  const int t = threadIdx.x;
  const int b = blockIdx.y;
  const int e0 = blockIdx.x * 32;
  const int w = t >> 6, l = t & 63, q = l >> 4, lm = l & 15;

  // ---- A-tile DMA: issue FIRST (async, zero VGPR cost) ----
  const float* eab = ea + (size_t)b * E_CNT * 128;
#pragma unroll
  for (int i = 0; i < 4; ++i) {
    const int p = i * 256 + w * 64 + l;      // physical granule 0..1023
    const int e = p >> 5;                    // local edge 0..31
    const int g = (p & 31) ^ (e & 7);        // logical granule (source swizzle)
    const float* src = eab + ((size_t)(e0 + e)) * 128 + g * 4;
    char* dst = (char*)U + (i * 4096 + w * 1024);   // wave-uniform base
    gld16(src, dst);
  }

  // ---- phase 0: stage xg (gather), sh, slot ids (overlaps DMA) ----
  if (t < 128) {
    const int el = t >> 2, i0 = (t & 3) * 4;
    const int src = eidx[e0 + el];
    const float4 v = *(const float4*)(xnew + ((size_t)b * N_CNT + src) * 16 + i0);
    xgs[el * 20 + i0 + 0] = v.x;
    xgs[el * 20 + i0 + 1] = v.y;
    xgs[el * 20 + i0 + 2] = v.z;
    xgs[el * 20 + i0 + 3] = v.w;
  } else if (t < 160) {
    const int el = t - 128;
    const float4 v = *(const float4*)(esh + ((size_t)b * E_CNT + e0 + el) * 4);
    shs[el * 4 + 0] = v.x;
    shs[el * 4 + 1] = v.y;
    shs[el * 4 + 2] = v.z;
    shs[el * 4 + 3] = v.w;
  } else if (t < 192) {
    const int el = t - 160;
    ids[el] = idx_arr[e0 + el];
  }

  // B-fragments for GEMM1 (L2-resident; overlap with DMA)
  s16x8 bfr[2][4];
#pragma unroll
  for (int j = 0; j < 2; ++j)
#pragma unroll
    for (int kk = 0; kk < 4; ++kk)
      bfr[j][kk] = *(const s16x8*)(pw1 + (((size_t)(2 * w + j) * 4 + kk) * 64 + l) * 8);

  __syncthreads();   // barrier 0: A-tile DMA + staging complete

  // ---- GEMM1: A from LDS (conflict-free swizzled reads) ----
  f32x4 acc1[2][2];
#pragma unroll
  for (int mt = 0; mt < 2; ++mt)
#pragma unroll
    for (int j = 0; j < 2; ++j) acc1[mt][j] = (f32x4)0.0f;

  const int s7 = lm & 7;
#pragma unroll
  for (int kk = 0; kk < 4; ++kk) {
#pragma unroll
    for (int mt = 0; mt < 2; ++mt) {
      const int el = mt * 16 + lm;
      const int g1 = kk * 8 + q * 2;
      const float4 a0 = *(const float4*)&Af[el * 128 + ((g1 ^ s7) << 2)];
      const float4 a1 = *(const float4*)&Af[el * 128 + (((g1 + 1) ^ s7) << 2)];
      union { unsigned int u[4]; s16x8 s; } au;
      au.u[0] = cvtpk(a0.x, a0.y); au.u[1] = cvtpk(a0.z, a0.w);
      au.u[2] = cvtpk(a1.x, a1.y); au.u[3] = cvtpk(a1.z, a1.w);
      const s16x8 af = au.s;
      acc1[mt][0] = __builtin_amdgcn_mfma_f32_16x16x32_bf16(af, bfr[0][kk], acc1[mt][0], 0, 0, 0);
      acc1[mt][1] = __builtin_amdgcn_mfma_f32_16x16x32_bf16(af, bfr[1][kk], acc1[mt][1], 0, 0, 0);
    }
  }

  // prefetch GEMM2 B-fragments for kk=0 (independent of Hs)
  s16x8 bw0[6];
#pragma unroll
  for (int jj = 0; jj < 6; ++jj)
    bw0[jj] = *(const s16x8*)(pw2 + (((size_t)(6 * w + jj) * 4 + 0) * 64 + l) * 8);

  // ---- GEMM1 epilogue: bias+relu, pair-convert, scalar Hs stores ----
#pragma unroll
  for (int j = 0; j < 2; ++j) {
    const int n = (2 * w + j) * 16 + lm;
    const float bias = b1v[n];
#pragma unroll
    for (int mt = 0; mt < 2; ++mt) {
#pragma unroll
      for (int r = 0; r < 4; r += 2) {
        const float v0 = fmaxf(acc1[mt][j][r] + bias, 0.0f);
        const float v1 = fmaxf(acc1[mt][j][r + 1] + bias, 0.0f);
        const unsigned int pr = cvtpk(v0, v1);
        Hs[(mt * 16 + q * 4 + r) * 136 + n] = (unsigned short)pr;
        Hs[(mt * 16 + q * 4 + r + 1) * 136 + n] = (unsigned short)(pr >> 16);
      }
    }
  }
#pragma unroll
  for (int jj = 0; jj < 6; ++jj) keeps(bw0[jj]);   // pin across barrier
  __syncthreads();   // barrier 1: Hs ready (A-tile reads also done -> EWt may be written)

  // ---- GEMM2 ----
  f32x4 acc2[2][6];
#pragma unroll
  for (int mt = 0; mt < 2; ++mt)
#pragma unroll
    for (int jj = 0; jj < 6; ++jj) acc2[mt][jj] = (f32x4)0.0f;

#pragma unroll
  for (int kk = 0; kk < 4; ++kk) {
    s16x8 bw[6];
    if (kk == 0) {
#pragma unroll
      for (int jj = 0; jj < 6; ++jj) bw[jj] = bw0[jj];
    } else {
#pragma unroll
      for (int jj = 0; jj < 6; ++jj)
        bw[jj] = *(const s16x8*)(pw2 + (((size_t)(6 * w + jj) * 4 + kk) * 64 + l) * 8);
    }
#pragma unroll
    for (int mt = 0; mt < 2; ++mt) {
      const s16x8 ah = *(const s16x8*)(&Hs[(mt * 16 + lm) * 136 + kk * 32 + q * 8]);
#pragma unroll
      for (int jj = 0; jj < 6; ++jj)
        acc2[mt][jj] = __builtin_amdgcn_mfma_f32_16x16x32_bf16(ah, bw[jj], acc2[mt][jj], 0, 0, 0);
    }
  }

  // ---- epilogue 2: bias + cvt_pk, HALF-SWIZZLED b32 stores into EWt (=U) ----
  // logical: tile T=6w+jj: T<16 -> (ch=lm, i=T); T>=16 -> (ch=16+(lm>>1), i=8*(l&1)+T-16)
  // physical 16B-half = logical half ^ (q&1)
  float bias6[6];
#pragma unroll
  for (int jj = 0; jj < 6; ++jj) {
    const int T = 6 * w + jj;
    const int bcol = (T < 16) ? (T * 16 + lm)
                              : (256 + (8 * (l & 1) + (T - 16)) * 8 + (lm >> 1));
    bias6[jj] = b2v[bcol];
  }
  const int sq4 = (q & 1) * 4;          // swizzle offset for half 0
  const int nsq4 = 4 - sq4;             // swizzle offset for half 1
  const int ch2off = (16 + (lm >> 1)) * 8 + (((l & 1) ^ (q & 1)) ? 4 : 0);
#pragma unroll
  for (int mt = 0; mt < 2; ++mt)
#pragma unroll
    for (int r = 0; r < 4; ++r) {
      const int edge = mt * 16 + q * 4 + r;
      const unsigned int p0 = cvtpk(acc2[mt][0][r] + bias6[0], acc2[mt][1][r] + bias6[1]);
      const unsigned int p1 = cvtpk(acc2[mt][2][r] + bias6[2], acc2[mt][3][r] + bias6[3]);
      const unsigned int p2 = cvtpk(acc2[mt][4][r] + bias6[4], acc2[mt][5][r] + bias6[5]);
      unsigned int* base = (unsigned int*)&EWt[edge * 392];
      if (w == 0) {
        unsigned int* d = base + lm * 8 + sq4;
        d[0] = p0; d[1] = p1; d[2] = p2;
      } else if (w == 1) {
        base[lm * 8 + sq4 + 3] = p0;
        unsigned int* d = base + lm * 8 + nsq4;
        d[0] = p1; d[1] = p2;
      } else if (w == 2) {
        unsigned int* d = base + lm * 8 + nsq4 + 2;
        d[0] = p0; d[1] = p1;
        base[ch2off] = p2;
      } else {
        unsigned int* d = base + ch2off + 1;
        d[0] = p0; d[1] = p1; d[2] = p2;
      }
    }
  __syncthreads();   // barrier 2: EWt ready

  // ---- phase 3: 24 dots/edge, 3 per thread, half-swapped b128 LDS reads ----
  {
    const int m = t >> 3, sub = t & 7;
    const int sqr8 = ((m >> 2) & 1) << 3;    // read-side half swap
    float xr[16];
#pragma unroll
    for (int i0 = 0; i0 < 16; i0 += 4) {
      const float4 v = *(const float4*)&xgs[m * 20 + i0];
      xr[i0] = v.x; xr[i0 + 1] = v.y; xr[i0 + 2] = v.z; xr[i0 + 3] = v.w;
    }
    const float sh0v = 0.25f * shs[m * 4 + 0];   // ALPHA = 1/sqrt(16)
    const float s1a = 0.25f * shs[m * 4 + 1];
    const float s1b = 0.25f * shs[m * 4 + 2];
    const float s1c = 0.25f * shs[m * 4 + 3];
    float* outp = out_base + (size_t)b * bstride + (size_t)ids[m] * 40;
#pragma unroll
    for (int dd = 0; dd < 3; ++dd) {
      const int d = sub * 3 + dd;                // 0..23 == EWt channel
      const unsigned short* ep = &EWt[m * 392 + d * 16];
      const s16x8 eA = *(const s16x8*)(ep + sqr8);
      const s16x8 eB = *(const s16x8*)(ep + 8 - sqr8);
      float dotv = 0.f;
#pragma unroll
      for (int i = 0; i < 8; ++i) {
        dotv += xr[i] * b2f((unsigned short)eA[i]);
        dotv += xr[8 + i] * b2f((unsigned short)eB[i]);
      }
      if (d < 16) {
        const float val = dotv * sh0v;
        if (ATOMIC) atomicAdd(outp + d, val); else outp[d] = val;
      } else {
        const int c0 = 16 + (d - 16) * 3;
        if (ATOMIC) {
          atomicAdd(outp + c0 + 0, dotv * s1a);
          atomicAdd(outp + c0 + 1, dotv * s1b);
          atomicAdd(outp + c0 + 2, dotv * s1c);
        } else {
          outp[c0 + 0] = dotv * s1a;
          outp[c0 + 1] = dotv * s1b;
          outp[c0 + 2] = dotv * s1c;
        }
      }
    }
  }
}

// ---------------------------------------------------------------------------
// K5 (fallback only): agg = sums / max(cnt,1) + per-channel partials.
// ---------------------------------------------------------------------------
__global__ void k_agg(float* __restrict__ sums, const int* __restrict__ cnt,
                      float* __restrict__ psum, float* __restrict__ psq) {
  __shared__ float ls[40], lq[40];
  const int t = threadIdx.x;
  if (t < 40) { ls[t] = 0.f; lq[t] = 0.f; }
  __syncthreads();
  const unsigned base = blockIdx.x * 2048u + t;
  for (int k2 = 0; k2 < 8; ++k2) {
    const unsigned idx = base + k2 * 256u;
    if (idx < 1600000u) {
      const unsigned row = idx / 40u;
      const unsigned node = row % 10000u;
      const float c = (float)cnt[node];
      const float v = sums[idx] / fmaxf(c, 1.f);
      sums[idx] = v;
      const unsigned ch = idx - row * 40u;
      atomicAdd(&ls[ch], v);
      atomicAdd(&lq[ch], v * v);
    }
  }
  __syncthreads();
  if (t < 40) {
    atomicAdd(&psum[t], ls[t]);
    atomicAdd(&psq[t], lq[t]);
  }
}

// ---------------------------------------------------------------------------
// K5b (CSR): gather rows per (b,node), mean-divide, BN partials.
// ---------------------------------------------------------------------------
__global__ __launch_bounds__(256) void k_gather(
    const float* __restrict__ msgbuf, const int* __restrict__ rowstart,
    float* __restrict__ sums, float* __restrict__ psum, float* __restrict__ psq) {
  const int t = threadIdx.x;
  const int wid = t >> 6, ch = t & 63;
  if (ch >= 40) return;
  float lsum = 0.f, lsq = 0.f;
  for (int k = 0; k < 8; ++k) {
    const int p = blockIdx.x * 32 + wid * 8 + k;   // 0..39999 = b*10000+node
    const int bb = p / 10000;
    const int node = p - bb * 10000;
    const int r0 = rowstart[node], r1 = rowstart[node + 1];
    const float* base = msgbuf + (size_t)bb * (E_CNT * 40) + ch;
    float v0 = 0.f, v1 = 0.f, v2 = 0.f, v3 = 0.f;
    int r = r0;
    for (; r + 4 <= r1; r += 4) {
      v0 += base[(size_t)(r + 0) * 40];
      v1 += base[(size_t)(r + 1) * 40];
      v2 += base[(size_t)(r + 2) * 40];
      v3 += base[(size_t)(r + 3) * 40];
    }
    for (; r < r1; ++r) v0 += base[(size_t)r * 40];
    float v = (v0 + v1) + (v2 + v3);
    v /= fmaxf((float)(r1 - r0), 1.f);
    sums[(size_t)p * 40 + ch] = v;
    lsum += v; lsq += v * v;
  }
  atomicAdd(&psum[ch], lsum);
  atomicAdd(&psq[ch], lsq);
}

// ---------------------------------------------------------------------------
// K7: BN finalize (per-block, from partials) + normalize + fp32 output.
// ---------------------------------------------------------------------------
__global__ void k_out(const float* __restrict__ agg,
                      const float* __restrict__ psum, const float* __restrict__ psq,
                      const float* __restrict__ gma, const float* __restrict__ bta,
                      float* __restrict__ outp) {
  __shared__ float sc[40], sh[40];
  const int t = threadIdx.x;
  if (t < 40) {
    const float inv = 1.0f / 40000.0f;  // B*N rows
    const float mu = psum[t] * inv;
    const float var = psq[t] * inv - mu * mu;
    const float s = rsqrtf(fmaxf(var, 0.0f) + 1e-5f) * gma[t];
    sc[t] = s;
    sh[t] = bta[t] - mu * s;
  }
  __syncthreads();
  const unsigned base = blockIdx.x * 1024u + t;
#pragma unroll
  for (int k2 = 0; k2 < 4; ++k2) {
    const unsigned idx = base + k2 * 256u;
    if (idx < 1600000u) {
      const unsigned row = idx / 40u;
      const unsigned ch = idx - row * 40u;
      outp[idx] = agg[idx] * sc[ch] + sh[ch];
    }
  }
}

// ---------------------------------------------------------------------------
// Workspace layout (bytes):
//   [0)          sums      6,400,000   (CSR: written by k_gather; FB: zeroed)
//   [6,400,000)  cnt          40,000   (zeroed)
//   [6,440,000)  psum            160   (zeroed)
//   [6,440,160)  psq             160   (zeroed)
//   [6,440,448)  xnew      2,560,000
//   [9,000,448)  pw1          32,768
//   [9,033,216)  pw2          98,304
//   [9,131,840)  rowstart     40,016   (10001 ints)           } CSR only
//   [9,171,856)  runoff       40,000                          }
//   [9,211,856)  pos         400,000                          }
//   [9,611,904)  msgbuf   64,000,000                          }
// CSR total 73,611,904
// ---------------------------------------------------------------------------
extern "C" void kernel_launch(void* const* d_in, const int* in_sizes, int n_in,
                              void* d_out, int out_size, void* d_ws, size_t ws_size,
                              hipStream_t stream) {
  (void)in_sizes; (void)n_in; (void)out_size;
  const float* x    = (const float*)d_in[0];
  const int*   eidx = (const int*)d_in[1];
  const float* ea   = (const float*)d_in[2];
  const float* esh  = (const float*)d_in[3];
  const float* tcwr = (const float*)d_in[4];
  const float* tcwi = (const float*)d_in[5];
  const float* w1   = (const float*)d_in[6];
  const float* b1   = (const float*)d_in[7];
  const float* w2   = (const float*)d_in[8];
  const float* b2   = (const float*)d_in[9];
  const float* gma  = (const float*)d_in[10];
  const float* bta  = (const float*)d_in[11];

  char* ws = (char*)d_ws;
  float*          sums     = (float*)(ws + 0);
  int*            cnt      = (int*)(ws + 6400000);
  float*          psum     = (float*)(ws + 6440000);
  float*          psq      = (float*)(ws + 6440160);
  float*          xnew     = (float*)(ws + 6440448);
  unsigned short* pw1      = (unsigned short*)(ws + 9000448);
  unsigned short* pw2      = (unsigned short*)(ws + 9033216);
  int*            rowstart = (int*)(ws + 9131840);
  int*            runoff   = (int*)(ws + 9171856);
  int*            pos      = (int*)(ws + 9211856);
  float*          msgbuf   = (float*)(ws + 9611904);

  const bool use_csr = ws_size >= (size_t)73611904;

  if (use_csr) {
    hipMemsetAsync(ws + 6400000, 0, 40320, stream);  // cnt + psum + psq
    k_prep<<<dim3(463), dim3(256), 0, stream>>>(x, tcwr, tcwi, xnew, w1, w2,
                                                pw1, pw2, eidx, cnt);
    k_scan<<<dim3(1), dim3(256), 0, stream>>>(cnt, rowstart, runoff);
    k_pos<<<dim3(391), dim3(256), 0, stream>>>(eidx, runoff, pos);
    k_edge<false><<<dim3(E_CNT / 32, B_CNT), dim3(256), 0, stream>>>(
        ea, eidx, esh, pw1, pw2, b1, b2, xnew, pos, msgbuf, (size_t)E_CNT * 40);
    k_gather<<<dim3(1250), dim3(256), 0, stream>>>(msgbuf, rowstart, sums, psum, psq);
    k_out<<<dim3(1563), dim3(256), 0, stream>>>(sums, psum, psq, gma, bta, (float*)d_out);
  } else {
    hipMemsetAsync(ws, 0, 6440320, stream);
    k_prep<<<dim3(463), dim3(256), 0, stream>>>(x, tcwr, tcwi, xnew, w1, w2,
                                                pw1, pw2, eidx, cnt);
    k_edge<true><<<dim3(E_CNT / 32, B_CNT), dim3(256), 0, stream>>>(
        ea, eidx, esh, pw1, pw2, b1, b2, xnew, eidx + E_CNT, sums, (size_t)N_CNT * 40);
    k_agg<<<dim3(782), dim3(256), 0, stream>>>(sums, cnt, psum, psq);
    k_out<<<dim3(1563), dim3(256), 0, stream>>>(sums, psum, psq, gma, bta, (float*)d_out);
  }
}

// Round 7
// 511.730 us; speedup vs baseline: 1.3164x; 1.1512x over previous
//
#include <hip/hip_runtime.h>

#define B_CNT 4
#define N_CNT 10000
#define E_CNT 100000

typedef __attribute__((ext_vector_type(8))) short s16x8;
typedef __attribute__((ext_vector_type(4))) float f32x4;
typedef __attribute__((ext_vector_type(4))) unsigned int u32x4;

__device__ __forceinline__ float b2f(unsigned short u) {
  union { unsigned int i; float f; } v; v.i = ((unsigned int)u) << 16; return v.f;
}
__device__ __forceinline__ unsigned short f2b(float f) {
  union { float f; unsigned int i; } v; v.f = f;
  unsigned int b = v.i;
  b += 0x7FFFu + ((b >> 16) & 1u);   // round-to-nearest-even
  return (unsigned short)(b >> 16);
}
// packed fp32 pair -> bf16x2 (RNE), one VALU op
__device__ __forceinline__ unsigned int cvtpk(float lo, float hi) {
  unsigned int r;
  asm("v_cvt_pk_bf16_f32 %0, %1, %2" : "=v"(r) : "v"(lo), "v"(hi));
  return r;
}
__device__ __forceinline__ void keeps(s16x8 v) {
  u32x4 u = __builtin_bit_cast(u32x4, v);
  asm volatile("" :: "v"(u.x), "v"(u.y), "v"(u.z), "v"(u.w));
}
// async global->LDS DMA, 16 B per lane (dst = uniform base + lane*16)
__device__ __forceinline__ void gld16(const void* g, void* l) {
  __builtin_amdgcn_global_load_lds(
      (const __attribute__((address_space(1))) unsigned int*)g,
      (__attribute__((address_space(3))) unsigned int*)l, 16, 0, 0);
}

// ---------------------------------------------------------------------------
// K_PREP: fused {fft (blocks 0..39)} ∪ {pack (40..71)} ∪ {cnt (72..462)}.
// ---------------------------------------------------------------------------
__global__ void k_prep(const float* __restrict__ x,
                       const float* __restrict__ tcwr,
                       const float* __restrict__ tcwi,
                       float* __restrict__ xnew,
                       const float* __restrict__ w1,
                       const float* __restrict__ w2,
                       unsigned short* __restrict__ pw1,
                       unsigned short* __restrict__ pw2,
                       const int* __restrict__ eidx,
                       int* __restrict__ cnt) {
  const int bid = blockIdx.x;
  const int t = threadIdx.x;
  if (bid < 40) {
    // ---- spectral transform (closed-form rfft/irfft over batch, n=4) ----
    __shared__ float Wr[256], Wi[256];
    Wr[t] = tcwr[t * 2] + tcwr[t * 2 + 1];
    Wi[t] = tcwi[t * 2] + tcwi[t * 2 + 1];
    __syncthreads();
    const int n = bid * 256 + t;
    if (n >= N_CNT) return;
    float xt[4][16];
    for (int tt = 0; tt < 4; ++tt) {
      const float* xp = x + ((size_t)tt * N_CNT + n) * 16;
#pragma unroll
      for (int i0 = 0; i0 < 16; i0 += 4) {
        const float4 v = *(const float4*)(xp + i0);
        xt[tt][i0 + 0] = v.x; xt[tt][i0 + 1] = v.y;
        xt[tt][i0 + 2] = v.z; xt[tt][i0 + 3] = v.w;
      }
    }
    float s[16], a[16], bb[16];
#pragma unroll
    for (int i = 0; i < 16; ++i) {
      s[i]  = xt[0][i] + xt[1][i] + xt[2][i] + xt[3][i];
      a[i]  = xt[0][i] - xt[2][i];
      bb[i] = xt[1][i] - xt[3][i];
    }
    for (int o = 0; o < 16; ++o) {
      float r0 = 0.f, p = 0.f, qq = 0.f;
#pragma unroll
      for (int i = 0; i < 16; ++i) {
        const float wr = Wr[i * 16 + o], wi = Wi[i * 16 + o];
        r0 += s[i] * wr;
        p  += a[i] * wr + bb[i] * wi;
        qq += a[i] * wi - bb[i] * wr;
      }
      xnew[((size_t)0 * N_CNT + n) * 16 + o] = 0.25f * (r0 + 2.f * p);
      xnew[((size_t)1 * N_CNT + n) * 16 + o] = 0.25f * (r0 - 2.f * qq);
      xnew[((size_t)2 * N_CNT + n) * 16 + o] = 0.25f * (r0 - 2.f * p);
      xnew[((size_t)3 * N_CNT + n) * 16 + o] = 0.25f * (r0 + 2.f * qq);
    }
  } else if (bid < 72) {
    // ---- pack W1/W2 fp32 -> bf16 MFMA B-fragment order ----
    const int tg = (bid - 40) * 256 + t;  // 0..8191
    const int tile = tg >> 6, l = tg & 63, q = l >> 4, lm = l & 15;
    if (tile < 32) {
      const int nt = tile >> 2, kk = tile & 3;
      const int n = nt * 16 + lm;
      unsigned short* dst = pw1 + ((size_t)tile * 64 + l) * 8;
#pragma unroll
      for (int j = 0; j < 8; ++j) dst[j] = f2b(w1[(kk * 32 + q * 8 + j) * 128 + n]);
    } else {
      const int t2 = tile - 32;  // 0..95
      const int nt = t2 >> 2, kk = t2 & 3;
      int col;
      if (nt < 16) col = nt * 16 + lm;
      else col = 256 + (8 * (lm & 1) + (nt - 16)) * 8 + (lm >> 1);
      unsigned short* dst = pw2 + ((size_t)t2 * 64 + l) * 8;
#pragma unroll
      for (int j = 0; j < 8; ++j) dst[j] = f2b(w2[(kk * 32 + q * 8 + j) * 384 + col]);
    }
  } else {
    // ---- in-degree histogram ----
    const int e = (bid - 72) * 256 + t;
    if (e < E_CNT) atomicAdd(&cnt[eidx[E_CNT + e]], 1);
  }
}

// ---------------------------------------------------------------------------
// K_SCAN: exclusive prefix scan of cnt -> rowstart[10001], runoff copy.
// Wave shfl-scan replaces the serial 256-step LDS chain.
// ---------------------------------------------------------------------------
__global__ void k_scan(const int* __restrict__ cnt, int* __restrict__ rowstart,
                       int* __restrict__ runoff) {
  __shared__ int wsum[4];
  const int t = threadIdx.x;
  const int wid = t >> 6, ln = t & 63;
  const int c0 = t * 40;
  int s = 0;
  for (int j = 0; j < 40; ++j) {
    const int idx = c0 + j;
    if (idx < N_CNT) s += cnt[idx];
  }
  // wave-level inclusive scan
  int v = s;
#pragma unroll
  for (int off = 1; off < 64; off <<= 1) {
    const int u = __shfl_up(v, off);
    if (ln >= off) v += u;
  }
  if (ln == 63) wsum[wid] = v;
  __syncthreads();
  if (t == 0) {
    int a = 0;
    for (int i = 0; i < 4; ++i) { const int tv = wsum[i]; wsum[i] = a; a += tv; }
  }
  __syncthreads();
  int acc = v - s + wsum[wid];  // exclusive prefix for this thread's chunk
  for (int j = 0; j < 40; ++j) {
    const int idx = c0 + j;
    if (idx < N_CNT) { rowstart[idx] = acc; runoff[idx] = acc; acc += cnt[idx]; }
  }
  if (t == 255) rowstart[N_CNT] = acc;  // == E_CNT
}

// ---------------------------------------------------------------------------
// K_POS: per-edge slot assignment within its dst group (CSR permutation).
// ---------------------------------------------------------------------------
__global__ void k_pos(const int* __restrict__ eidx, int* __restrict__ runoff,
                      int* __restrict__ pos) {
  const int e = blockIdx.x * 256 + threadIdx.x;
  if (e < E_CNT) pos[e] = atomicAdd(&runoff[eidx[E_CNT + e]], 1);
}

// ---------------------------------------------------------------------------
// K4: fused edge kernel (UNCHANGED from R5: 164 us measured).
// ---------------------------------------------------------------------------
template <bool ATOMIC>
__global__ __launch_bounds__(256, 4) void k_edge(
    const float* __restrict__ ea, const int* __restrict__ eidx,
    const float* __restrict__ esh,
    const unsigned short* __restrict__ pw1, const unsigned short* __restrict__ pw2,
    const float* __restrict__ b1v, const float* __restrict__ b2v,
    const float* __restrict__ xnew, const int* __restrict__ idx_arr,
    float* __restrict__ out_base, const size_t bstride) {
  __shared__ __align__(16) unsigned short U[32 * 392];   // A-tile(16KB) ∪ EWt(25KB)
  __shared__ __align__(16) unsigned short Hs[32 * 136];  // [edge][k], +8 pad
  __shared__ float xgs[32 * 20];                         // 16 + 4 pad
  __shared__ float shs[32 * 4];
  __shared__ int ids[32];
  unsigned short* const EWt = U;
  const float* const Af = (const float*)U;

  const int t = threadIdx.x;
  const int b = blockIdx.y;
  const int e0 = blockIdx.x * 32;
  const int w = t >> 6, l = t & 63, q = l >> 4, lm = l & 15;

  // ---- A-tile DMA: issue FIRST (async, zero VGPR cost) ----
  const float* eab = ea + (size_t)b * E_CNT * 128;
#pragma unroll
  for (int i = 0; i < 4; ++i) {
    const int p = i * 256 + w * 64 + l;      // physical granule 0..1023
    const int e = p >> 5;                    // local edge 0..31
    const int g = (p & 31) ^ (e & 7);        // logical granule (source swizzle)
    const float* src = eab + ((size_t)(e0 + e)) * 128 + g * 4;
    char* dst = (char*)U + (i * 4096 + w * 1024);   // wave-uniform base
    gld16(src, dst);
  }

  // ---- phase 0: stage xg (gather), sh, slot ids (overlaps DMA) ----
  if (t < 128) {
    const int el = t >> 2, i0 = (t & 3) * 4;
    const int src = eidx[e0 + el];
    const float4 v = *(const float4*)(xnew + ((size_t)b * N_CNT + src) * 16 + i0);
    xgs[el * 20 + i0 + 0] = v.x;
    xgs[el * 20 + i0 + 1] = v.y;
    xgs[el * 20 + i0 + 2] = v.z;
    xgs[el * 20 + i0 + 3] = v.w;
  } else if (t < 160) {
    const int el = t - 128;
    const float4 v = *(const float4*)(esh + ((size_t)b * E_CNT + e0 + el) * 4);
    shs[el * 4 + 0] = v.x;
    shs[el * 4 + 1] = v.y;
    shs[el * 4 + 2] = v.z;
    shs[el * 4 + 3] = v.w;
  } else if (t < 192) {
    const int el = t - 160;
    ids[el] = idx_arr[e0 + el];
  }

  // B-fragments for GEMM1 (L2-resident; overlap with DMA)
  s16x8 bfr[2][4];
#pragma unroll
  for (int j = 0; j < 2; ++j)
#pragma unroll
    for (int kk = 0; kk < 4; ++kk)
      bfr[j][kk] = *(const s16x8*)(pw1 + (((size_t)(2 * w + j) * 4 + kk) * 64 + l) * 8);

  __syncthreads();   // barrier 0: A-tile DMA + staging complete

  // ---- GEMM1: A from LDS (conflict-free swizzled reads) ----
  f32x4 acc1[2][2];
#pragma unroll
  for (int mt = 0; mt < 2; ++mt)
#pragma unroll
    for (int j = 0; j < 2; ++j) acc1[mt][j] = (f32x4)0.0f;

  const int s7 = lm & 7;
#pragma unroll
  for (int kk = 0; kk < 4; ++kk) {
#pragma unroll
    for (int mt = 0; mt < 2; ++mt) {
      const int el = mt * 16 + lm;
      const int g1 = kk * 8 + q * 2;
      const float4 a0 = *(const float4*)&Af[el * 128 + ((g1 ^ s7) << 2)];
      const float4 a1 = *(const float4*)&Af[el * 128 + (((g1 + 1) ^ s7) << 2)];
      union { unsigned int u[4]; s16x8 s; } au;
      au.u[0] = cvtpk(a0.x, a0.y); au.u[1] = cvtpk(a0.z, a0.w);
      au.u[2] = cvtpk(a1.x, a1.y); au.u[3] = cvtpk(a1.z, a1.w);
      const s16x8 af = au.s;
      acc1[mt][0] = __builtin_amdgcn_mfma_f32_16x16x32_bf16(af, bfr[0][kk], acc1[mt][0], 0, 0, 0);
      acc1[mt][1] = __builtin_amdgcn_mfma_f32_16x16x32_bf16(af, bfr[1][kk], acc1[mt][1], 0, 0, 0);
    }
  }

  // prefetch GEMM2 B-fragments for kk=0 (independent of Hs)
  s16x8 bw0[6];
#pragma unroll
  for (int jj = 0; jj < 6; ++jj)
    bw0[jj] = *(const s16x8*)(pw2 + (((size_t)(6 * w + jj) * 4 + 0) * 64 + l) * 8);

  // ---- GEMM1 epilogue: bias+relu, pair-convert, scalar Hs stores ----
#pragma unroll
  for (int j = 0; j < 2; ++j) {
    const int n = (2 * w + j) * 16 + lm;
    const float bias = b1v[n];
#pragma unroll
    for (int mt = 0; mt < 2; ++mt) {
#pragma unroll
      for (int r = 0; r < 4; r += 2) {
        const float v0 = fmaxf(acc1[mt][j][r] + bias, 0.0f);
        const float v1 = fmaxf(acc1[mt][j][r + 1] + bias, 0.0f);
        const unsigned int pr = cvtpk(v0, v1);
        Hs[(mt * 16 + q * 4 + r) * 136 + n] = (unsigned short)pr;
        Hs[(mt * 16 + q * 4 + r + 1) * 136 + n] = (unsigned short)(pr >> 16);
      }
    }
  }
#pragma unroll
  for (int jj = 0; jj < 6; ++jj) keeps(bw0[jj]);   // pin across barrier
  __syncthreads();   // barrier 1: Hs ready (A-tile reads done -> EWt may be written)

  // ---- GEMM2 ----
  f32x4 acc2[2][6];
#pragma unroll
  for (int mt = 0; mt < 2; ++mt)
#pragma unroll
    for (int jj = 0; jj < 6; ++jj) acc2[mt][jj] = (f32x4)0.0f;

#pragma unroll
  for (int kk = 0; kk < 4; ++kk) {
    s16x8 bw[6];
    if (kk == 0) {
#pragma unroll
      for (int jj = 0; jj < 6; ++jj) bw[jj] = bw0[jj];
    } else {
#pragma unroll
      for (int jj = 0; jj < 6; ++jj)
        bw[jj] = *(const s16x8*)(pw2 + (((size_t)(6 * w + jj) * 4 + kk) * 64 + l) * 8);
    }
#pragma unroll
    for (int mt = 0; mt < 2; ++mt) {
      const s16x8 ah = *(const s16x8*)(&Hs[(mt * 16 + lm) * 136 + kk * 32 + q * 8]);
#pragma unroll
      for (int jj = 0; jj < 6; ++jj)
        acc2[mt][jj] = __builtin_amdgcn_mfma_f32_16x16x32_bf16(ah, bw[jj], acc2[mt][jj], 0, 0, 0);
    }
  }

  // ---- epilogue 2: bias + cvt_pk, HALF-SWIZZLED b32 stores into EWt (=U) ----
  float bias6[6];
#pragma unroll
  for (int jj = 0; jj < 6; ++jj) {
    const int T = 6 * w + jj;
    const int bcol = (T < 16) ? (T * 16 + lm)
                              : (256 + (8 * (l & 1) + (T - 16)) * 8 + (lm >> 1));
    bias6[jj] = b2v[bcol];
  }
  const int sq4 = (q & 1) * 4;          // swizzle offset for half 0
  const int nsq4 = 4 - sq4;             // swizzle offset for half 1
  const int ch2off = (16 + (lm >> 1)) * 8 + (((l & 1) ^ (q & 1)) ? 4 : 0);
#pragma unroll
  for (int mt = 0; mt < 2; ++mt)
#pragma unroll
    for (int r = 0; r < 4; ++r) {
      const int edge = mt * 16 + q * 4 + r;
      const unsigned int p0 = cvtpk(acc2[mt][0][r] + bias6[0], acc2[mt][1][r] + bias6[1]);
      const unsigned int p1 = cvtpk(acc2[mt][2][r] + bias6[2], acc2[mt][3][r] + bias6[3]);
      const unsigned int p2 = cvtpk(acc2[mt][4][r] + bias6[4], acc2[mt][5][r] + bias6[5]);
      unsigned int* base = (unsigned int*)&EWt[edge * 392];
      if (w == 0) {
        unsigned int* d = base + lm * 8 + sq4;
        d[0] = p0; d[1] = p1; d[2] = p2;
      } else if (w == 1) {
        base[lm * 8 + sq4 + 3] = p0;
        unsigned int* d = base + lm * 8 + nsq4;
        d[0] = p1; d[1] = p2;
      } else if (w == 2) {
        unsigned int* d = base + lm * 8 + nsq4 + 2;
        d[0] = p0; d[1] = p1;
        base[ch2off] = p2;
      } else {
        unsigned int* d = base + ch2off + 1;
        d[0] = p0; d[1] = p1; d[2] = p2;
      }
    }
  __syncthreads();   // barrier 2: EWt ready

  // ---- phase 3: 24 dots/edge, 3 per thread, half-swapped b128 LDS reads ----
  {
    const int m = t >> 3, sub = t & 7;
    const int sqr8 = ((m >> 2) & 1) << 3;    // read-side half swap
    float xr[16];
#pragma unroll
    for (int i0 = 0; i0 < 16; i0 += 4) {
      const float4 v = *(const float4*)&xgs[m * 20 + i0];
      xr[i0] = v.x; xr[i0 + 1] = v.y; xr[i0 + 2] = v.z; xr[i0 + 3] = v.w;
    }
    const float sh0v = 0.25f * shs[m * 4 + 0];   // ALPHA = 1/sqrt(16)
    const float s1a = 0.25f * shs[m * 4 + 1];
    const float s1b = 0.25f * shs[m * 4 + 2];
    const float s1c = 0.25f * shs[m * 4 + 3];
    float* outp = out_base + (size_t)b * bstride + (size_t)ids[m] * 40;
#pragma unroll
    for (int dd = 0; dd < 3; ++dd) {
      const int d = sub * 3 + dd;                // 0..23 == EWt channel
      const unsigned short* ep = &EWt[m * 392 + d * 16];
      const s16x8 eA = *(const s16x8*)(ep + sqr8);
      const s16x8 eB = *(const s16x8*)(ep + 8 - sqr8);
      float dotv = 0.f;
#pragma unroll
      for (int i = 0; i < 8; ++i) {
        dotv += xr[i] * b2f((unsigned short)eA[i]);
        dotv += xr[8 + i] * b2f((unsigned short)eB[i]);
      }
      if (d < 16) {
        const float val = dotv * sh0v;
        if (ATOMIC) atomicAdd(outp + d, val); else outp[d] = val;
      } else {
        const int c0 = 16 + (d - 16) * 3;
        if (ATOMIC) {
          atomicAdd(outp + c0 + 0, dotv * s1a);
          atomicAdd(outp + c0 + 1, dotv * s1b);
          atomicAdd(outp + c0 + 2, dotv * s1c);
        } else {
          outp[c0 + 0] = dotv * s1a;
          outp[c0 + 1] = dotv * s1b;
          outp[c0 + 2] = dotv * s1c;
        }
      }
    }
  }
}

// ---------------------------------------------------------------------------
// K5 (fallback only): agg = sums / max(cnt,1) + per-channel partials.
// ---------------------------------------------------------------------------
__global__ void k_agg(float* __restrict__ sums, const int* __restrict__ cnt,
                      float* __restrict__ psum, float* __restrict__ psq) {
  __shared__ float ls[40], lq[40];
  const int t = threadIdx.x;
  if (t < 40) { ls[t] = 0.f; lq[t] = 0.f; }
  __syncthreads();
  const unsigned base = blockIdx.x * 2048u + t;
  for (int k2 = 0; k2 < 8; ++k2) {
    const unsigned idx = base + k2 * 256u;
    if (idx < 1600000u) {
      const unsigned row = idx / 40u;
      const unsigned node = row % 10000u;
      const float c = (float)cnt[node];
      const float v = sums[idx] / fmaxf(c, 1.f);
      sums[idx] = v;
      const unsigned ch = idx - row * 40u;
      atomicAdd(&ls[ch], v);
      atomicAdd(&lq[ch], v * v);
    }
  }
  __syncthreads();
  if (t < 40) {
    atomicAdd(&psum[t], ls[t]);
    atomicAdd(&psq[t], lq[t]);
  }
}

// ---------------------------------------------------------------------------
// K5b (CSR): gather rows per (b,node) — ONE WAVE PER NODE-SEGMENT.
// Wave reads the contiguous segment [r0*40, r1*40) at lane-stride 64
// (coalesced, 16 independent predicated loads). Element seg[l+64i] has
// channel (l+24*(i%5)) mod 40 -> 5 register accumulators per lane,
// merged via LDS atomics into lacc[wid][40].
// FIX (R6 bug): chj range reduction now covers c in [0,160) — previous
// version left c in [40,80) for c>=120, corrupting neighboring LDS.
// ---------------------------------------------------------------------------
__global__ __launch_bounds__(256) void k_gather(
    const float* __restrict__ msgbuf, const int* __restrict__ rowstart,
    float* __restrict__ sums, float* __restrict__ psum, float* __restrict__ psq) {
  __shared__ float lacc[4][40];
  __shared__ float bsum[40], bsq[40];
  const int t = threadIdx.x;
  const int wid = t >> 6, l = t & 63;
  if (t < 40) { bsum[t] = 0.f; bsq[t] = 0.f; }
  __syncthreads();

  // per-lane channel map: racc[j] accumulates ch = (l + 24*j) mod 40
  int chj[5];
#pragma unroll
  for (int j = 0; j < 5; ++j) {
    int c = l + 24 * j;            // 0..159
    if (c >= 120) c -= 120;
    else if (c >= 80) c -= 80;
    else if (c >= 40) c -= 40;
    chj[j] = c;
  }

  float lpsum = 0.f, lpsq = 0.f;
  for (int k = 0; k < 8; ++k) {
    const int p = blockIdx.x * 32 + wid * 8 + k;   // 0..39999 = b*10000+node
    const int bb = p / 10000;
    const int node = p - bb * 10000;
    const int r0 = rowstart[node], r1 = rowstart[node + 1];
    const int d = r1 - r0;
    const int L = d * 40;
    const float* seg = msgbuf + (size_t)bb * (E_CNT * 40) + (size_t)r0 * 40;

    if (l < 40) lacc[wid][l] = 0.f;

    float racc[5] = {0.f, 0.f, 0.f, 0.f, 0.f};
#pragma unroll
    for (int i = 0; i < 16; ++i) {           // covers degree <= 25 (common case)
      const int base = l + i * 64;
      if (base < L) racc[i % 5] += seg[base];
    }
    int base = l + 16 * 64;                  // rare tail, static racc indices
    while (base < L) {
      racc[1] += seg[base]; base += 64;
      if (base < L) { racc[2] += seg[base]; base += 64; } else break;
      if (base < L) { racc[3] += seg[base]; base += 64; } else break;
      if (base < L) { racc[4] += seg[base]; base += 64; } else break;
      if (base < L) { racc[0] += seg[base]; base += 64; } else break;
    }
#pragma unroll
    for (int j = 0; j < 5; ++j) atomicAdd(&lacc[wid][chj[j]], racc[j]);

    if (l < 40) {
      const float v = lacc[wid][l] / fmaxf((float)d, 1.0f);
      sums[(size_t)p * 40 + l] = v;
      lpsum += v; lpsq += v * v;
    }
  }
  if (l < 40) {
    atomicAdd(&bsum[l], lpsum);
    atomicAdd(&bsq[l], lpsq);
  }
  __syncthreads();
  if (t < 40) {
    atomicAdd(&psum[t], bsum[t]);
    atomicAdd(&psq[t], bsq[t]);
  }
}

// ---------------------------------------------------------------------------
// K7: BN finalize (per-block, from partials) + normalize + fp32 output.
// ---------------------------------------------------------------------------
__global__ void k_out(const float* __restrict__ agg,
                      const float* __restrict__ psum, const float* __restrict__ psq,
                      const float* __restrict__ gma, const float* __restrict__ bta,
                      float* __restrict__ outp) {
  __shared__ float sc[40], sh[40];
  const int t = threadIdx.x;
  if (t < 40) {
    const float inv = 1.0f / 40000.0f;  // B*N rows
    const float mu = psum[t] * inv;
    const float var = psq[t] * inv - mu * mu;
    const float s = rsqrtf(fmaxf(var, 0.0f) + 1e-5f) * gma[t];
    sc[t] = s;
    sh[t] = bta[t] - mu * s;
  }
  __syncthreads();
  const unsigned base = blockIdx.x * 1024u + t;
#pragma unroll
  for (int k2 = 0; k2 < 4; ++k2) {
    const unsigned idx = base + k2 * 256u;
    if (idx < 1600000u) {
      const unsigned row = idx / 40u;
      const unsigned ch = idx - row * 40u;
      outp[idx] = agg[idx] * sc[ch] + sh[ch];
    }
  }
}

// ---------------------------------------------------------------------------
// Workspace layout (bytes):
//   [0)          sums      6,400,000   (CSR: written by k_gather; FB: zeroed)
//   [6,400,000)  cnt          40,000   (zeroed)
//   [6,440,000)  psum            160   (zeroed)
//   [6,440,160)  psq             160   (zeroed)
//   [6,440,448)  xnew      2,560,000
//   [9,000,448)  pw1          32,768
//   [9,033,216)  pw2          98,304
//   [9,131,840)  rowstart     40,016   (10001 ints)           } CSR only
//   [9,171,856)  runoff       40,000                          }
//   [9,211,856)  pos         400,000                          }
//   [9,611,904)  msgbuf   64,000,000                          }
// CSR total 73,611,904
// ---------------------------------------------------------------------------
extern "C" void kernel_launch(void* const* d_in, const int* in_sizes, int n_in,
                              void* d_out, int out_size, void* d_ws, size_t ws_size,
                              hipStream_t stream) {
  (void)in_sizes; (void)n_in; (void)out_size;
  const float* x    = (const float*)d_in[0];
  const int*   eidx = (const int*)d_in[1];
  const float* ea   = (const float*)d_in[2];
  const float* esh  = (const float*)d_in[3];
  const float* tcwr = (const float*)d_in[4];
  const float* tcwi = (const float*)d_in[5];
  const float* w1   = (const float*)d_in[6];
  const float* b1   = (const float*)d_in[7];
  const float* w2   = (const float*)d_in[8];
  const float* b2   = (const float*)d_in[9];
  const float* gma  = (const float*)d_in[10];
  const float* bta  = (const float*)d_in[11];

  char* ws = (char*)d_ws;
  float*          sums     = (float*)(ws + 0);
  int*            cnt      = (int*)(ws + 6400000);
  float*          psum     = (float*)(ws + 6440000);
  float*          psq      = (float*)(ws + 6440160);
  float*          xnew     = (float*)(ws + 6440448);
  unsigned short* pw1      = (unsigned short*)(ws + 9000448);
  unsigned short* pw2      = (unsigned short*)(ws + 9033216);
  int*            rowstart = (int*)(ws + 9131840);
  int*            runoff   = (int*)(ws + 9171856);
  int*            pos      = (int*)(ws + 9211856);
  float*          msgbuf   = (float*)(ws + 9611904);

  const bool use_csr = ws_size >= (size_t)73611904;

  if (use_csr) {
    hipMemsetAsync(ws + 6400000, 0, 40320, stream);  // cnt + psum + psq
    k_prep<<<dim3(463), dim3(256), 0, stream>>>(x, tcwr, tcwi, xnew, w1, w2,
                                                pw1, pw2, eidx, cnt);
    k_scan<<<dim3(1), dim3(256), 0, stream>>>(cnt, rowstart, runoff);
    k_pos<<<dim3(391), dim3(256), 0, stream>>>(eidx, runoff, pos);
    k_edge<false><<<dim3(E_CNT / 32, B_CNT), dim3(256), 0, stream>>>(
        ea, eidx, esh, pw1, pw2, b1, b2, xnew, pos, msgbuf, (size_t)E_CNT * 40);
    k_gather<<<dim3(1250), dim3(256), 0, stream>>>(msgbuf, rowstart, sums, psum, psq);
    k_out<<<dim3(1563), dim3(256), 0, stream>>>(sums, psum, psq, gma, bta, (float*)d_out);
  } else {
    hipMemsetAsync(ws, 0, 6440320, stream);
    k_prep<<<dim3(463), dim3(256), 0, stream>>>(x, tcwr, tcwi, xnew, w1, w2,
                                                pw1, pw2, eidx, cnt);
    k_edge<true><<<dim3(E_CNT / 32, B_CNT), dim3(256), 0, stream>>>(
        ea, eidx, esh, pw1, pw2, b1, b2, xnew, eidx + E_CNT, sums, (size_t)N_CNT * 40);
    k_agg<<<dim3(782), dim3(256), 0, stream>>>(sums, cnt, psum, psq);
    k_out<<<dim3(1563), dim3(256), 0, stream>>>(sums, psum, psq, gma, bta, (float*)d_out);
  }
}